// Round 1
// baseline (360.974 us; speedup 1.0000x reference)
//
#include <hip/hip_runtime.h>
#include <math.h>

#define BROWS 65536
#define LLEN  1024
#define KW    16
#define NPOS  (LLEN - KW + 1)     // 1009 valid conv outputs
#define RPB   4                   // waves per block (independent, no barriers)
#define NBLOCKS 2048
#define ROWS_PER_WAVE (BROWS / (NBLOCKS * RPB))   // 8

typedef float f4 __attribute__((ext_vector_type(4)));

// Each lane owns 16 conv outputs starting at 16*lane; it needs the 32 floats
// x[16*lane .. 16*lane+31]. Loaded DIRECTLY from global as 8 float4s.
// Adjacent lanes overlap by 16 floats -> the row is read ~2x, but the second
// read is L1-resident (row = 4 KB << 32 KB L1); HBM cache-line traffic is 1x.
// Lane 63's upper half runs past the row end: clamp the address in-row; the
// garbage values only feed conv positions >= NPOS, predicated out below.
__device__ __forceinline__ void load_row(const float* __restrict__ xr,
                                         int fbase, float* __restrict__ buf) {
#pragma unroll
    for (int j = 0; j < 8; ++j) {
        int off = fbase + 4 * j;
        off = (off > LLEN - 4) ? (LLEN - 4) : off;   // only lane 63, j>=4
        *(f4*)(&buf[4 * j]) = *(const f4*)(xr + off);
    }
}

__device__ __forceinline__ float conv_max(const float* __restrict__ xv,
                                          const float* __restrict__ wv,
                                          int own) {
    float vmax = -INFINITY;
#pragma unroll
    for (int pp = 0; pp < KW; ++pp) {
        float acc = 0.0f;
#pragma unroll
        for (int k = 0; k < KW; ++k) acc = fmaf(xv[pp + k], wv[k], acc);
        if (own + pp < NPOS) vmax = fmaxf(vmax, acc);   // tail predicated
    }
    return vmax;
}

__device__ __forceinline__ void finish_row(float vmax, int lane, float bv,
                                           const float* __restrict__ lo,
                                           const float* __restrict__ hi,
                                           int fb, int* __restrict__ out,
                                           int row) {
    // wave-wide max reduction (6 ds_swizzles — the only LDS-pipe use left)
#pragma unroll
    for (int off = 32; off > 0; off >>= 1)
        vmax = fmaxf(vmax, __shfl_xor(vmax, off, 64));
    if (lane == 0) {
        const float v = fmaxf(vmax + bv, 0.0f);
        // first range match wins -> iterate descending so lowest j lands last
        int label = fb;                       // precomputed constant fallback
#pragma unroll
        for (int j = 3; j >= 0; --j)
            label = (v >= lo[j] && v <= hi[j]) ? j : label;
        out[row] = label;
    }
}

__global__ __launch_bounds__(256) void conv_pool_classify(
    const float* __restrict__ x,       // (B, 1, L)
    const float* __restrict__ w,       // (1, 1, K)
    const float* __restrict__ bias,    // (1,)
    const float* __restrict__ ranges,  // (4, 2) row-major
    int* __restrict__ out)             // (B,1,1) labels as int32
{
    const int lane  = threadIdx.x & 63;
    const int wid   = threadIdx.x >> 6;
    const int wave  = blockIdx.x * RPB + wid;
    const int row0  = wave * ROWS_PER_WAVE;
    const int fbase = 16 * lane;

    // ---- hoisted uniforms: filter, bias, ranges, constant fallback label ----
    float wv[KW];
#pragma unroll
    for (int k = 0; k < KW; ++k) wv[k] = w[k];
    const float bv = bias[0];

    float rr[8];
#pragma unroll
    for (int j = 0; j < 8; ++j) rr[j] = ranges[j];
    // argmin_j sqrt(v*v + rr[j]) == argmin_j rr[j]  (monotone, v^2 constant)
    // -> fallback label is a kernel-wide constant. Strict < keeps first match,
    //    matching jnp.argmin semantics.
    int fb = 0; float bm = rr[0];
#pragma unroll
    for (int j = 1; j < 8; ++j) { if (rr[j] < bm) { bm = rr[j]; fb = j; } }
    fb >>= 1;
    const float lo[4] = {rr[0], rr[2], rr[4], rr[6]};
    const float hi[4] = {rr[1], rr[3], rr[5], rr[7]};

    // ---- software-pipelined row loop, double-buffered in registers ----
    float bufA[32], bufB[32];
    load_row(x + (size_t)row0 * LLEN, fbase, bufA);

#pragma unroll 1
    for (int it = 0; it < ROWS_PER_WAVE; it += 2) {
        // issue row it+1 loads; they fly under row it's 256 FMAs
        load_row(x + (size_t)(row0 + it + 1) * LLEN, fbase, bufB);
        const float m0 = conv_max(bufA, wv, fbase);
        finish_row(m0, lane, bv, lo, hi, fb, out, row0 + it);

        if (it + 2 < ROWS_PER_WAVE)
            load_row(x + (size_t)(row0 + it + 2) * LLEN, fbase, bufA);
        const float m1 = conv_max(bufB, wv, fbase);
        finish_row(m1, lane, bv, lo, hi, fb, out, row0 + it + 1);
    }
}

extern "C" void kernel_launch(void* const* d_in, const int* in_sizes, int n_in,
                              void* d_out, int out_size, void* d_ws, size_t ws_size,
                              hipStream_t stream) {
    const float* x      = (const float*)d_in[0];
    const float* w      = (const float*)d_in[1];
    const float* bias   = (const float*)d_in[2];
    const float* ranges = (const float*)d_in[3];
    int* out = (int*)d_out;

    dim3 grid(NBLOCKS);   // 2048 blocks x 4 waves x 8 rows/wave = 65536 rows
    dim3 block(256);
    conv_pool_classify<<<grid, block, 0, stream>>>(x, w, bias, ranges, out);
}

// Round 2
// 337.764 us; speedup vs baseline: 1.0687x; 1.0687x over previous
//
#include <hip/hip_runtime.h>
#include <math.h>

#define BROWS 65536
#define LLEN  1024
#define KW    16
#define NPOS  (LLEN - KW + 1)     // 1009 valid conv outputs
#define RPB   4                   // waves per block (independent, no barrier)
#define NBLOCKS 2048
#define ROWS_PER_WAVE (BROWS / (NBLOCKS * RPB))   // 8

// Native vector type for __builtin_nontemporal_load (HIP_vector_type rejected).
typedef float nt_float4 __attribute__((ext_vector_type(4)));

// XOR swizzle on float4-granule index: involution, keeps 16B alignment,
// spreads bank-start quads so both staging writes (lane-contiguous) and
// window reads (granule = 4*lane+j) are near-conflict-free.
__device__ __forceinline__ int swz(int g) { return g ^ ((g >> 3) & 7); }

__global__ __launch_bounds__(256) void conv_pool_classify(
    const float* __restrict__ x,       // (B, 1, L)
    const float* __restrict__ w,       // (1, 1, K)
    const float* __restrict__ bias,    // (1,)
    const float* __restrict__ ranges,  // (4, 2) row-major
    int* __restrict__ out)             // (B,1,1) labels as int32
{
    __shared__ nt_float4 lds[RPB][LLEN / 4];   // 4 KB private per wave

    const int lane = threadIdx.x & 63;
    const int wid  = threadIdx.x >> 6;
    const int wave = blockIdx.x * RPB + wid;
    const int row0 = wave * ROWS_PER_WAVE;

    // ---- filter + bias + ranges hoisted to registers (lane-uniform) ----
    float wv[KW];
#pragma unroll
    for (int k = 0; k < KW; ++k) wv[k] = w[k];
    const float bv = bias[0];

    float rr[8];
#pragma unroll
    for (int j = 0; j < 8; ++j) rr[j] = ranges[j];
    // Fallback: argmin_j sqrt(v*v + rr[j]) == argmin_j rr[j] (monotone in rr,
    // v^2 per-row constant) -> kernel-wide constant label. Strict < keeps the
    // FIRST minimum, matching jnp.argmin tie semantics.
    int fb = 0; float bm = rr[0];
#pragma unroll
    for (int j = 1; j < 8; ++j) { if (rr[j] < bm) { bm = rr[j]; fb = j; } }
    fb >>= 1;
    const float lo[4] = {rr[0], rr[2], rr[4], rr[6]};
    const float hi[4] = {rr[1], rr[3], rr[5], rr[7]};

    // ---- prefetch first row into registers (nontemporal: streamed once) ----
    nt_float4 p[4];
    {
        const float* __restrict__ xr = x + (size_t)row0 * LLEN;
#pragma unroll
        for (int s = 0; s < 4; ++s)
            p[s] = __builtin_nontemporal_load((const nt_float4*)(xr + 256 * s + 4 * lane));
    }

    int mylbl = 0;   // lane `it` parks row row0+it's label here

    for (int it = 0; it < ROWS_PER_WAVE; ++it) {
        // ---- stage prefetched row to this wave's private LDS region ----
        // (same-wave ds_write -> ds_read is in-order via lgkmcnt; no barrier)
#pragma unroll
        for (int s = 0; s < 4; ++s)
            lds[wid][swz(64 * s + lane)] = p[s];

        // ---- issue next row's global loads; they fly during compute ----
        if (it + 1 < ROWS_PER_WAVE) {
            const float* __restrict__ xr = x + (size_t)(row0 + it + 1) * LLEN;
#pragma unroll
            for (int s = 0; s < 4; ++s)
                p[s] = __builtin_nontemporal_load((const nt_float4*)(xr + 256 * s + 4 * lane));
        }

        // ---- each lane pulls its 32-float window from LDS ----
        float xv[32];
#pragma unroll
        for (int j = 0; j < 8; ++j) {
            int g = 4 * lane + j;
            if (g > 255) g = 255;            // lane 63 tail clamp (values unused)
            *(nt_float4*)(&xv[4 * j]) = lds[wid][swz(g)];
        }

        // ---- 16 conv outputs per lane, running max, tail predicated ----
        const int own = 16 * lane;
        float vmax = -INFINITY;
#pragma unroll
        for (int pp = 0; pp < KW; ++pp) {
            float acc = 0.0f;
#pragma unroll
            for (int k = 0; k < KW; ++k) acc = fmaf(xv[pp + k], wv[k], acc);
            vmax = ((own + pp) < NPOS) ? fmaxf(vmax, acc) : vmax;
        }

        // ---- wave-wide max reduction (all lanes end up with the max) ----
#pragma unroll
        for (int off = 32; off > 0; off >>= 1)
            vmax = fmaxf(vmax, __shfl_xor(vmax, off, 64));

        // ---- classify in registers (all lanes, uniform; no memory) ----
        const float v = fmaxf(vmax + bv, 0.0f);
        int label = fb;
#pragma unroll
        for (int j = 3; j >= 0; --j)
            label = (v >= lo[j] && v <= hi[j]) ? j : label;   // first match wins
        if (lane == it) mylbl = label;
    }

    // ---- one coalesced 32B store per wave (8 consecutive int32 labels) ----
    if (lane < ROWS_PER_WAVE) out[row0 + lane] = mylbl;
}

extern "C" void kernel_launch(void* const* d_in, const int* in_sizes, int n_in,
                              void* d_out, int out_size, void* d_ws, size_t ws_size,
                              hipStream_t stream) {
    const float* x      = (const float*)d_in[0];
    const float* w      = (const float*)d_in[1];
    const float* bias   = (const float*)d_in[2];
    const float* ranges = (const float*)d_in[3];
    int* out = (int*)d_out;

    dim3 grid(NBLOCKS);   // 2048 blocks x 4 waves x 8 rows/wave = 65536 rows
    dim3 block(256);
    conv_pool_classify<<<grid, block, 0, stream>>>(x, w, bias, ranges, out);
}